// Round 3
// baseline (1822.894 us; speedup 1.0000x reference)
//
#include <hip/hip_runtime.h>

// GraphSAGE 2-layer inference, MI355X.
// Inputs: x[N,256] f32, edge_src[E] i32, edge_dst[E] i32, edge_val[E] f32 (unused; recomputed),
//         W1[512,256] f32, b1[256] f32, W2[512,128] f32, b2[128] f32.
// Output: [N,128] f32 (row L2-normalized).

#define N_NODES 100000
#define N_EDGES 3200000
#define DF      256          // feature dim (D_IN == D_HID)
#define K2      512          // 2*DF concat dim

// ------------------------- CSR build -------------------------

__global__ void k_hist(const int* __restrict__ src, int* __restrict__ deg, int E){
  int i = blockIdx.x * blockDim.x + threadIdx.x;
  if(i < E) atomicAdd(&deg[src[i]], 1);
}

// per-block exclusive scan over 1024-element chunks (256 thr x 4)
__global__ void k_scan1(const int* __restrict__ deg, int* __restrict__ rowptr,
                        int* __restrict__ partials, int n){
  __shared__ int s[256];
  const int t = threadIdx.x;
  const int base = blockIdx.x * 1024 + t * 4;
  int v[4], run[4];
  #pragma unroll
  for(int j = 0; j < 4; j++) v[j] = (base + j < n) ? deg[base + j] : 0;
  int sum = 0;
  #pragma unroll
  for(int j = 0; j < 4; j++){ run[j] = sum; sum += v[j]; }
  s[t] = sum;
  __syncthreads();
  for(int off = 1; off < 256; off <<= 1){
    int x = (t >= off) ? s[t - off] : 0;
    __syncthreads();
    s[t] += x;
    __syncthreads();
  }
  const int texcl = s[t] - sum;
  #pragma unroll
  for(int j = 0; j < 4; j++) if(base + j < n) rowptr[base + j] = texcl + run[j];
  if(t == 255) partials[blockIdx.x] = s[255];
}

// single-block exclusive scan of block partials (nb <= 128); also sets rowptr[n]=E
__global__ void k_scan2(int* __restrict__ partials, int nb,
                        int* __restrict__ rowptr, int n, int E){
  __shared__ int s[128];
  const int t = threadIdx.x;
  int v = (t < nb) ? partials[t] : 0;
  s[t] = v;
  __syncthreads();
  for(int off = 1; off < 128; off <<= 1){
    int x = (t >= off) ? s[t - off] : 0;
    __syncthreads();
    s[t] += x;
    __syncthreads();
  }
  if(t < nb) partials[t] = s[t] - v;   // exclusive
  if(t == 0) rowptr[n] = E;
}

__global__ void k_scan3(int* __restrict__ rowptr, const int* __restrict__ partials, int n){
  int i = blockIdx.x * blockDim.x + threadIdx.x;
  if(i < n) rowptr[i] += partials[i >> 10];
}

__global__ void k_fill(const int* __restrict__ src, const int* __restrict__ dst,
                       const int* __restrict__ rowptr, int* __restrict__ cursor,
                       int* __restrict__ col, int E){
  int i = blockIdx.x * blockDim.x + threadIdx.x;
  if(i < E){
    int r = src[i];
    int p = atomicAdd(&cursor[r], 1);
    col[rowptr[r] + p] = dst[i];
  }
}

// ------------------------- fused SAGE layer -------------------------
// Per block: 32 nodes. Phase A: gather mean-neighbor + self into comb[32][512] (LDS).
// Phase B: comb @ W (f32 register tile, 4 nodes x CPT cols per thread).
// Phase C: +bias, row L2-normalize via shfl reduce, optional ReLU, store.

__device__ __forceinline__ float f4get(const float4& v, int j){
  return (j == 0) ? v.x : (j == 1) ? v.y : (j == 2) ? v.z : v.w;
}

template<int DOUT, bool RELU>
__launch_bounds__(256, 2)
__global__ void k_sage(const float* __restrict__ feat,
                       const float* __restrict__ Wm,
                       const float* __restrict__ bias,
                       const int*  __restrict__ rowptr,
                       const int*  __restrict__ colidx,
                       float* __restrict__ outp)
{
  __shared__ __align__(16) float comb[32][K2];   // 64 KiB -> 2 blocks/CU
  const int t     = threadIdx.x;
  const int node0 = blockIdx.x * 32;             // N % 32 == 0, no tail
  const int wave  = t >> 6;
  const int lane  = t & 63;
  const float4* f4 = (const float4*)feat;

  // ---- Phase A: each wave owns nodes {wave, wave+4, ...}; 64 lanes x float4 = one 256-f row
  for(int n = wave; n < 32; n += 4){
    const int node = node0 + n;
    const float4 sf = f4[(size_t)node * (DF/4) + lane];
    const int s0 = rowptr[node];
    const int s1 = rowptr[node + 1];
    const float invd = (s1 > s0) ? (1.0f / (float)(s1 - s0)) : 0.0f;
    float ax = 0.f, ay = 0.f, az = 0.f, aw = 0.f;
    int e = s0;
    for(; e + 4 <= s1; e += 4){     // 4 independent row loads in flight
      const int c0 = colidx[e+0], c1 = colidx[e+1], c2 = colidx[e+2], c3 = colidx[e+3];
      const float4 va = f4[(size_t)c0 * (DF/4) + lane];
      const float4 vb = f4[(size_t)c1 * (DF/4) + lane];
      const float4 vc = f4[(size_t)c2 * (DF/4) + lane];
      const float4 vd = f4[(size_t)c3 * (DF/4) + lane];
      ax += va.x + vb.x + vc.x + vd.x;
      ay += va.y + vb.y + vc.y + vd.y;
      az += va.z + vb.z + vc.z + vd.z;
      aw += va.w + vb.w + vc.w + vd.w;
    }
    for(; e < s1; ++e){
      const float4 va = f4[(size_t)colidx[e] * (DF/4) + lane];
      ax += va.x; ay += va.y; az += va.z; aw += va.w;
    }
    float4 nb;
    nb.x = ax * invd; nb.y = ay * invd; nb.z = az * invd; nb.w = aw * invd;
    *(float4*)&comb[n][lane * 4]      = sf;   // self  -> dims [0,256)
    *(float4*)&comb[n][DF + lane * 4] = nb;   // neigh -> dims [256,512)
  }
  __syncthreads();

  // ---- Phase B: GEMM. thread (ng, cg): nodes ng*4..+4, cols cg*CPT..+CPT
  constexpr int CPT = DOUT / 32;   // 8 (DOUT=256) or 4 (DOUT=128)
  constexpr int CQ  = CPT / 4;
  const int cg = t & 31;
  const int ng = t >> 5;
  const int nodeb = ng * 4;
  const int col0  = cg * CPT;
  const float4* W4 = (const float4*)Wm;

  float acc[4][CPT];
  #pragma unroll
  for(int ni = 0; ni < 4; ni++)
    #pragma unroll
    for(int cj = 0; cj < CPT; cj++) acc[ni][cj] = 0.0f;

  for(int k = 0; k < K2; k += 4){
    float4 cv[4];
    #pragma unroll
    for(int ni = 0; ni < 4; ni++) cv[ni] = *(const float4*)&comb[nodeb + ni][k];
    float4 wr[4][CQ];
    #pragma unroll
    for(int kk = 0; kk < 4; kk++)
      #pragma unroll
      for(int q = 0; q < CQ; q++)
        wr[kk][q] = W4[(size_t)(k + kk) * (DOUT/4) + cg * CQ + q];
    #pragma unroll
    for(int kk = 0; kk < 4; kk++){
      float cn[4];
      #pragma unroll
      for(int ni = 0; ni < 4; ni++) cn[ni] = f4get(cv[ni], kk);
      #pragma unroll
      for(int ni = 0; ni < 4; ni++){
        #pragma unroll
        for(int q = 0; q < CQ; q++){
          acc[ni][q*4+0] = fmaf(cn[ni], wr[kk][q].x, acc[ni][q*4+0]);
          acc[ni][q*4+1] = fmaf(cn[ni], wr[kk][q].y, acc[ni][q*4+1]);
          acc[ni][q*4+2] = fmaf(cn[ni], wr[kk][q].z, acc[ni][q*4+2]);
          acc[ni][q*4+3] = fmaf(cn[ni], wr[kk][q].w, acc[ni][q*4+3]);
        }
      }
    }
  }

  // ---- Phase C: bias, L2-normalize (32-lane shfl reduce), ReLU, store
  float bv[CPT];
  #pragma unroll
  for(int cj = 0; cj < CPT; cj++) bv[cj] = bias[col0 + cj];

  #pragma unroll
  for(int ni = 0; ni < 4; ni++){
    float ssq = 0.0f;
    #pragma unroll
    for(int cj = 0; cj < CPT; cj++){
      acc[ni][cj] += bv[cj];
      ssq = fmaf(acc[ni][cj], acc[ni][cj], ssq);
    }
    // reduce across the 32 cg lanes (masks < 32 keep ng bit intact)
    ssq += __shfl_xor(ssq, 1);
    ssq += __shfl_xor(ssq, 2);
    ssq += __shfl_xor(ssq, 4);
    ssq += __shfl_xor(ssq, 8);
    ssq += __shfl_xor(ssq, 16);
    const float rn = 1.0f / fmaxf(sqrtf(ssq), 1e-12f);
    const int node = node0 + nodeb + ni;
    float4* o4 = (float4*)(outp + (size_t)node * DOUT);
    #pragma unroll
    for(int q = 0; q < CQ; q++){
      float4 v;
      v.x = acc[ni][q*4+0] * rn;
      v.y = acc[ni][q*4+1] * rn;
      v.z = acc[ni][q*4+2] * rn;
      v.w = acc[ni][q*4+3] * rn;
      if(RELU){
        v.x = fmaxf(v.x, 0.0f); v.y = fmaxf(v.y, 0.0f);
        v.z = fmaxf(v.z, 0.0f); v.w = fmaxf(v.w, 0.0f);
      }
      o4[cg * CQ + q] = v;
    }
  }
}

// ------------------------- host launch -------------------------

extern "C" void kernel_launch(void* const* d_in, const int* in_sizes, int n_in,
                              void* d_out, int out_size, void* d_ws, size_t ws_size,
                              hipStream_t stream) {
  const float* x    = (const float*)d_in[0];
  const int*   esrc = (const int*)  d_in[1];
  const int*   edst = (const int*)  d_in[2];
  // d_in[3] edge_val: unused — it is exactly 1/deg(src), recomputed from CSR
  const float* W1   = (const float*)d_in[4];
  const float* b1   = (const float*)d_in[5];
  const float* W2   = (const float*)d_in[6];
  const float* b2   = (const float*)d_in[7];
  float* out = (float*)d_out;

  const int N = N_NODES, E = N_EDGES;

  // workspace layout (256B-aligned slices)
  char* ws = (char*)d_ws;
  size_t off = 0;
  auto alloc = [&](size_t bytes) -> void* {
    void* p = ws + off;
    off += (bytes + 255) & ~(size_t)255;
    return p;
  };
  int*   deg      = (int*)  alloc((size_t)N * 4);
  int*   rowptr   = (int*)  alloc((size_t)(N + 1) * 4);
  int*   cursor   = (int*)  alloc((size_t)N * 4);
  int*   partials = (int*)  alloc(512);
  int*   colidx   = (int*)  alloc((size_t)E * 4);
  float* h        = (float*)alloc((size_t)N * DF * 4);
  if(off > ws_size) return;   // workspace too small — cannot run safely

  const int NBLK_SCAN = (N + 1023) / 1024;   // 98

  hipMemsetAsync(deg,    0, (size_t)N * 4, stream);
  hipMemsetAsync(cursor, 0, (size_t)N * 4, stream);

  k_hist <<<(E + 255) / 256, 256, 0, stream>>>(esrc, deg, E);
  k_scan1<<<NBLK_SCAN,       256, 0, stream>>>(deg, rowptr, partials, N);
  k_scan2<<<1,               128, 0, stream>>>(partials, NBLK_SCAN, rowptr, N, E);
  k_scan3<<<(N + 255) / 256, 256, 0, stream>>>(rowptr, partials, N);
  k_fill <<<(E + 255) / 256, 256, 0, stream>>>(esrc, edst, rowptr, cursor, colidx, E);

  // layer 1: x -> h (normalize + ReLU), layer 2: h -> out (normalize)
  k_sage<256, true ><<<N / 32, 256, 0, stream>>>(x, W1, b1, rowptr, colidx, h);
  k_sage<128, false><<<N / 32, 256, 0, stream>>>(h, W2, b2, rowptr, colidx, out);
}